// Round 1
// baseline (9407.178 us; speedup 1.0000x reference)
//
#include <hip/hip_runtime.h>
#include <float.h>
#include <math.h>

// ---------------------------------------------------------------------------
// MABlock: q/k/v/w projections -> attn over batch keys -> FAISS-style exact
// top-8 retrieval from FIFO memory -> attn over retrieved keys -> Wo + gate.
//
// Design notes (round 1):
//  * fp32 VALU GEMMs (128x128 tile, 8x8/thread, xor-swizzled LDS).
//  * Exact branch-and-bound search: top-8 over the 2048 new keys, then
//    Cauchy-Schwarz bound |q|*maxOldNorm vs val8 decides whether the old
//    30720 memory rows must be scanned (never triggers on this data, but the
//    fallback is exact, so correctness holds for any input).
//  * Flash attention via MFMA 16x16x32 bf16 with split-bf16 (hi+lo) inputs:
//    scores = qh*kh + ql*kh + qh*kl (error ~2^-17), PV = P*(Vh) + P*(Vl),
//    P single bf16 (softmax weights; random +-2^-9 relative -> ~2e-4 out).
//  * Workspace (floats): q,k,v,wg (4*SZ) | AO (2*SZ) | G (2*SZ) | idx | norms
// ---------------------------------------------------------------------------

#define DIN   1024
#define NHEADS 16
#define HD    64
#define NB    4
#define NSEQ  512
#define BN    2048          // NB*NSEQ
#define MEMN  32768
#define OLDN  30720         // MEMN - BN
#define IPQ   8
#define ATT_SCALE 0.125f
#define SZ    (BN * DIN)    // 2097152 floats

typedef __attribute__((ext_vector_type(4))) float floatx4;
typedef __attribute__((ext_vector_type(8))) short short8;

__device__ __forceinline__ unsigned short f2bf(float f) {
    unsigned int u = __float_as_uint(f);
    return (unsigned short)((u + 0x7FFFu + ((u >> 16) & 1u)) >> 16);
}
__device__ __forceinline__ float bf2f(unsigned short s) {
    return __uint_as_float(((unsigned int)s) << 16);
}
__device__ __forceinline__ void split_pack(float4 a, float4 b, short8 &hi, short8 &lo) {
    float vals[8] = {a.x, a.y, a.z, a.w, b.x, b.y, b.z, b.w};
#pragma unroll
    for (int j = 0; j < 8; ++j) {
        unsigned short h = f2bf(vals[j]);
        hi[j] = (short)h;
        lo[j] = (short)f2bf(vals[j] - bf2f(h));
    }
}
__device__ __forceinline__ floatx4 mfma16(short8 a, short8 b, floatx4 c) {
    return __builtin_amdgcn_mfma_f32_16x16x32_bf16(a, b, c, 0, 0, 0);
}

// ---------------------------------------------------------------------------
// init: zero the 16 per-head max-old-norm slots (ws is poisoned 0xAA)
// ---------------------------------------------------------------------------
__global__ void init_kernel(unsigned int* nrm) {
    if (threadIdx.x < NHEADS) nrm[threadIdx.x] = 0u;
}

// ---------------------------------------------------------------------------
// GEMM: C[z][M][1024] = A[M][1024] @ W[z][1024][1024]^T  (NT, both k-major)
// 128x128 tile, 256 threads, 8x8 accum/thread, K-chunks of 32 staged in LDS
// with xor swizzle (r + r>>3)&7 on float4 columns to kill bank conflicts.
// sigmoidZ: z index that gets a sigmoid epilogue (-1 = none).
// ---------------------------------------------------------------------------
__global__ __launch_bounds__(256, 2) void gemm128(
    const float* __restrict__ A,
    const float* __restrict__ W0, const float* __restrict__ W1,
    const float* __restrict__ W2, const float* __restrict__ W3,
    float* __restrict__ C0, float* __restrict__ C1,
    float* __restrict__ C2, float* __restrict__ C3,
    int sigmoidZ)
{
    __shared__ float4 As[128 * 9];
    __shared__ float4 Bs[128 * 9];
    int z = blockIdx.z;
    const float* W = (z == 0) ? W0 : (z == 1) ? W1 : (z == 2) ? W2 : W3;
    float* C = (z == 0) ? C0 : (z == 1) ? C1 : (z == 2) ? C2 : C3;
    int tid = threadIdx.x;
    int row0 = blockIdx.y * 128, col0 = blockIdx.x * 128;
    int ty = tid >> 4, tx = tid & 15;
    int sc4 = tid & 7;            // staging: f4 column 0..7
    int srow = tid >> 3;          // staging: 32 rows per pass, 4 passes

    float acc[8][8];
#pragma unroll
    for (int i = 0; i < 8; ++i)
#pragma unroll
        for (int j = 0; j < 8; ++j) acc[i][j] = 0.f;

    for (int kk = 0; kk < DIN; kk += 32) {
        __syncthreads();
#pragma unroll
        for (int p = 0; p < 4; ++p) {
            int r = p * 32 + srow;
            int sw = (r + (r >> 3)) & 7;
            As[r * 9 + (sc4 ^ sw)] = *(const float4*)(A + (size_t)(row0 + r) * DIN + kk + sc4 * 4);
            Bs[r * 9 + (sc4 ^ sw)] = *(const float4*)(W + (size_t)(col0 + r) * DIN + kk + sc4 * 4);
        }
        __syncthreads();
#pragma unroll
        for (int k4 = 0; k4 < 8; ++k4) {
            float4 a[8], b[8];
#pragma unroll
            for (int i = 0; i < 8; ++i)
                a[i] = As[(ty * 8 + i) * 9 + (k4 ^ ((i + ty) & 7))];
#pragma unroll
            for (int j = 0; j < 8; ++j)
                b[j] = Bs[(tx * 8 + j) * 9 + (k4 ^ ((j + tx) & 7))];
#pragma unroll
            for (int i = 0; i < 8; ++i)
#pragma unroll
                for (int j = 0; j < 8; ++j)
                    acc[i][j] += a[i].x * b[j].x + a[i].y * b[j].y
                               + a[i].z * b[j].z + a[i].w * b[j].w;
        }
    }
    bool sig = (sigmoidZ == z);
#pragma unroll
    for (int i = 0; i < 8; ++i) {
        float* crow = C + (size_t)(row0 + ty * 8 + i) * DIN + col0 + tx * 8;
#pragma unroll
        for (int j = 0; j < 8; ++j) {
            float vv = acc[i][j];
            if (sig) vv = 1.f / (1.f + __expf(-vv));
            crow[j] = vv;
        }
    }
}

// ---------------------------------------------------------------------------
// per-head max L2 norm over the 30720 surviving old memory keys
// grid (30, 16), 256 threads; 16 lanes per row.
// ---------------------------------------------------------------------------
__global__ __launch_bounds__(256) void oldnorm_kernel(
    const float* __restrict__ kmem0, unsigned int* __restrict__ nrm)
{
    int h = blockIdx.y;
    int c0 = blockIdx.x * 1024;
    int part = threadIdx.x & 15, rg = threadIdx.x >> 4;
    const float* base = kmem0 + ((size_t)h * MEMN + BN) * HD;
    float mx = 0.f;
    for (int it = 0; it < 64; ++it) {
        int row = c0 + it * 16 + rg;
        float4 vv = *(const float4*)(base + (size_t)row * HD + part * 4);
        float s = vv.x * vv.x + vv.y * vv.y + vv.z * vv.z + vv.w * vv.w;
#pragma unroll
        for (int o = 1; o < 16; o <<= 1) s += __shfl_xor(s, o, 16);
        mx = fmaxf(mx, s);
    }
    __shared__ float red[256];
    red[threadIdx.x] = mx;
    __syncthreads();
    for (int st = 128; st > 0; st >>= 1) {
        if (threadIdx.x < st) red[threadIdx.x] = fmaxf(red[threadIdx.x], red[threadIdx.x + st]);
        __syncthreads();
    }
    if (threadIdx.x == 0) atomicMax(nrm + h, __float_as_uint(sqrtf(red[0])));
}

// ---------------------------------------------------------------------------
// search: per (h, 32-query block) exact top-8.
// Phase A: scan the 2048 new keys (chunks of 128 staged in LDS).
// Merge per query over its 32-lane group (val desc, idx asc — matches top_k).
// Bound check |q|*maxOldNorm >= val8 -> exact old-memory scan (fallback).
// ---------------------------------------------------------------------------
__device__ __forceinline__ void insert_top8(float (&tv)[8], int (&ti)[8], float v, int id) {
    if (v < tv[7] || (v == tv[7] && id > ti[7])) return;
    tv[7] = v; ti[7] = id;
#pragma unroll
    for (int s = 7; s > 0; --s) {
        bool sw = (tv[s] > tv[s - 1]) || (tv[s] == tv[s - 1] && ti[s] < ti[s - 1]);
        if (sw) {
            float fv = tv[s]; tv[s] = tv[s - 1]; tv[s - 1] = fv;
            int iv = ti[s]; ti[s] = ti[s - 1]; ti[s - 1] = iv;
        }
    }
}

__global__ __launch_bounds__(256, 2) void search_kernel(
    const float* __restrict__ q, const float* __restrict__ knew,
    const float* __restrict__ kmem0, const unsigned int* __restrict__ nrm,
    int* __restrict__ idxOut)
{
    __shared__ float qT[32 * 68];
    __shared__ float Kc[128 * 68];
    __shared__ float qn2s[32];
    __shared__ int sflag;
    int h = blockIdx.y;
    int t0 = blockIdx.x * 32;
    int tid = threadIdx.x;
    int qg = tid >> 5;   // 0..7, queries qg*4..+4
    int kt = tid & 31;   // key thread 0..31, keys kt+32u
    if (tid == 0) sflag = 0;

    { // stage 32 query rows
        int c4 = tid & 15, r = tid >> 4;
#pragma unroll
        for (int p = 0; p < 2; ++p) {
            int row = p * 16 + r;
            float4 vv = *(const float4*)(q + (size_t)(t0 + row) * DIN + h * HD + c4 * 4);
            int sw = (row + (row >> 3)) & 7;
            *(float4*)&qT[row * 68 + ((c4 ^ sw) << 2)] = vv;
        }
    }
    __syncthreads();
    if (tid < 32) { // |q|^2 (order-independent: sum all physical slots)
        float s = 0.f;
#pragma unroll
        for (int c4 = 0; c4 < 16; ++c4) {
            float4 vv = *(const float4*)&qT[tid * 68 + c4 * 4];
            s += vv.x * vv.x + vv.y * vv.y + vv.z * vv.z + vv.w * vv.w;
        }
        qn2s[tid] = s;
    }

    float tv[4][8]; int ti[4][8];
#pragma unroll
    for (int qi = 0; qi < 4; ++qi)
#pragma unroll
        for (int s = 0; s < 8; ++s) { tv[qi][s] = -FLT_MAX; ti[qi][s] = 0x7FFFFFFF; }

    // ---- phase A: new keys ----
    for (int ch = 0; ch < 16; ++ch) {
        __syncthreads();
        {
            int c4 = tid & 15, r = tid >> 4;
#pragma unroll
            for (int p = 0; p < 8; ++p) {
                int row = p * 16 + r;
                float4 vv = *(const float4*)(knew + (size_t)(ch * 128 + row) * DIN + h * HD + c4 * 4);
                int sw = (row + (row >> 3)) & 7;
                *(float4*)&Kc[row * 68 + ((c4 ^ sw) << 2)] = vv;
            }
        }
        __syncthreads();
        float ps[4][4];
#pragma unroll
        for (int a = 0; a < 4; ++a)
#pragma unroll
            for (int b = 0; b < 4; ++b) ps[a][b] = 0.f;
        for (int c4 = 0; c4 < 16; ++c4) {
            float4 qf[4], kf[4];
#pragma unroll
            for (int qi = 0; qi < 4; ++qi) {
                int tq = qg * 4 + qi;
                qf[qi] = *(const float4*)&qT[tq * 68 + ((c4 ^ ((tq + (tq >> 3)) & 7)) << 2)];
            }
#pragma unroll
            for (int u = 0; u < 4; ++u) {
                int kr = kt + 32 * u;
                kf[u] = *(const float4*)&Kc[kr * 68 + ((c4 ^ ((kr + (kr >> 3)) & 7)) << 2)];
            }
#pragma unroll
            for (int qi = 0; qi < 4; ++qi)
#pragma unroll
                for (int u = 0; u < 4; ++u)
                    ps[qi][u] += qf[qi].x * kf[u].x + qf[qi].y * kf[u].y
                               + qf[qi].z * kf[u].z + qf[qi].w * kf[u].w;
        }
#pragma unroll
        for (int qi = 0; qi < 4; ++qi)
#pragma unroll
            for (int u = 0; u < 4; ++u)
                insert_top8(tv[qi], ti[qi], ps[qi][u], OLDN + ch * 128 + kt + 32 * u);
    }

    // ---- merge #1 (consumes lists; captures winners for possible rebuild) ----
    float val8[4], keepv[4];
    int keepi[4];
#pragma unroll
    for (int qi = 0; qi < 4; ++qi) { keepv[qi] = -FLT_MAX; keepi[qi] = 0x7FFFFFFF; val8[qi] = -FLT_MAX; }
#pragma unroll
    for (int qi = 0; qi < 4; ++qi) {
#pragma unroll
        for (int r = 0; r < 8; ++r) {
            float cv = tv[qi][0]; int ci = ti[qi][0];
#pragma unroll
            for (int o = 1; o < 32; o <<= 1) {
                float ov = __shfl_xor(cv, o, 32);
                int oi = __shfl_xor(ci, o, 32);
                if (ov > cv || (ov == cv && oi < ci)) { cv = ov; ci = oi; }
            }
            if (tv[qi][0] == cv && ti[qi][0] == ci) {
#pragma unroll
                for (int s = 0; s < 7; ++s) { tv[qi][s] = tv[qi][s + 1]; ti[qi][s] = ti[qi][s + 1]; }
                tv[qi][7] = -FLT_MAX; ti[qi][7] = 0x7FFFFFFF;
            }
            if (kt == r) { keepv[qi] = cv; keepi[qi] = ci; }
            if (kt == 0) idxOut[((size_t)h * BN + t0 + qg * 4 + qi) * IPQ + r] = ci;
            val8[qi] = cv;
        }
    }

    // ---- bound check: can any old key enter the top-8? ----
    float oldMax = __uint_as_float(nrm[h]);
    bool need = false;
#pragma unroll
    for (int qi = 0; qi < 4; ++qi) {
        float bnd = sqrtf(qn2s[qg * 4 + qi]) * oldMax * 1.0001f + 1e-5f;
        if (bnd >= val8[qi]) need = true;
    }
    if (need) sflag = 1;
    __syncthreads();

    if (sflag) {
        // rebuild per-lane lists: lane r<8 holds winner r, rest empty
#pragma unroll
        for (int qi = 0; qi < 4; ++qi) {
            tv[qi][0] = (kt < 8) ? keepv[qi] : -FLT_MAX;
            ti[qi][0] = (kt < 8) ? keepi[qi] : 0x7FFFFFFF;
#pragma unroll
            for (int s = 1; s < 8; ++s) { tv[qi][s] = -FLT_MAX; ti[qi][s] = 0x7FFFFFFF; }
        }
        for (int ch = 0; ch < 240; ++ch) {
            __syncthreads();
            {
                int c4 = tid & 15, r = tid >> 4;
#pragma unroll
                for (int p = 0; p < 8; ++p) {
                    int row = p * 16 + r;
                    float4 vv = *(const float4*)(kmem0 + ((size_t)h * MEMN + BN + ch * 128 + row) * HD + c4 * 4);
                    int sw = (row + (row >> 3)) & 7;
                    *(float4*)&Kc[row * 68 + ((c4 ^ sw) << 2)] = vv;
                }
            }
            __syncthreads();
            float ps[4][4];
#pragma unroll
            for (int a = 0; a < 4; ++a)
#pragma unroll
                for (int b = 0; b < 4; ++b) ps[a][b] = 0.f;
            for (int c4 = 0; c4 < 16; ++c4) {
                float4 qf[4], kf[4];
#pragma unroll
                for (int qi = 0; qi < 4; ++qi) {
                    int tq = qg * 4 + qi;
                    qf[qi] = *(const float4*)&qT[tq * 68 + ((c4 ^ ((tq + (tq >> 3)) & 7)) << 2)];
                }
#pragma unroll
                for (int u = 0; u < 4; ++u) {
                    int kr = kt + 32 * u;
                    kf[u] = *(const float4*)&Kc[kr * 68 + ((c4 ^ ((kr + (kr >> 3)) & 7)) << 2)];
                }
#pragma unroll
                for (int qi = 0; qi < 4; ++qi)
#pragma unroll
                    for (int u = 0; u < 4; ++u)
                        ps[qi][u] += qf[qi].x * kf[u].x + qf[qi].y * kf[u].y
                                   + qf[qi].z * kf[u].z + qf[qi].w * kf[u].w;
            }
#pragma unroll
            for (int qi = 0; qi < 4; ++qi)
#pragma unroll
                for (int u = 0; u < 4; ++u)
                    insert_top8(tv[qi], ti[qi], ps[qi][u], ch * 128 + kt + 32 * u);
        }
        // merge #2 (final)
#pragma unroll
        for (int qi = 0; qi < 4; ++qi) {
#pragma unroll
            for (int r = 0; r < 8; ++r) {
                float cv = tv[qi][0]; int ci = ti[qi][0];
#pragma unroll
                for (int o = 1; o < 32; o <<= 1) {
                    float ov = __shfl_xor(cv, o, 32);
                    int oi = __shfl_xor(ci, o, 32);
                    if (ov > cv || (ov == cv && oi < ci)) { cv = ov; ci = oi; }
                }
                if (tv[qi][0] == cv && ti[qi][0] == ci) {
#pragma unroll
                    for (int s = 0; s < 7; ++s) { tv[qi][s] = tv[qi][s + 1]; ti[qi][s] = ti[qi][s + 1]; }
                    tv[qi][7] = -FLT_MAX; ti[qi][7] = 0x7FFFFFFF;
                }
                if (kt == 0) idxOut[((size_t)h * BN + t0 + qg * 4 + qi) * IPQ + r] = ci;
            }
        }
    }
}

// ---------------------------------------------------------------------------
// MFMA flash attention. Block = 4 waves x 16 queries = 64 queries per (b,h).
// Per 32-key chunk: stage K (hi/lo bf16, row-major) and V^T (hi/lo, dim-major)
// in LDS; S = QK^T via 3-product split-bf16 mfma; online softmax per wave
// (quad-row layout, width-16 shuffles); P round-trips LDS to A-frag layout;
// O += P*Vhi + P*Vlo.  gatherMode=1 resolves rows through idx (memory attn).
// ---------------------------------------------------------------------------
__global__ __launch_bounds__(256, 2) void attn_kernel(
    const float* __restrict__ q, const float* __restrict__ knew,
    const float* __restrict__ vnew, const float* __restrict__ kmem0,
    const float* __restrict__ vmem0, const int* __restrict__ idxb,
    float* __restrict__ outp, int gatherMode, int nkeys)
{
    __shared__ short Khi[32 * 72];
    __shared__ short Klo[32 * 72];
    __shared__ short Vthi[64 * 40];
    __shared__ short Vtlo[64 * 40];
    __shared__ short Pbuf[4 * 16 * 40];
    int tid = threadIdx.x;
    int qt = blockIdx.x, h = blockIdx.y, b = blockIdx.z;
    int wv = tid >> 6, lane = tid & 63, quad = lane >> 4, l16 = lane & 15;

    // persistent Q fragments (A-operand layout: row=l16, k=quad*8+j, step*32)
    short8 qhi[2], qlo[2];
    {
        int qrow = b * NSEQ + qt * 64 + wv * 16 + l16;
        const float* qp = q + (size_t)qrow * DIN + h * HD;
#pragma unroll
        for (int st = 0; st < 2; ++st) {
            float4 a = *(const float4*)(qp + st * 32 + quad * 8);
            float4 c = *(const float4*)(qp + st * 32 + quad * 8 + 4);
            split_pack(a, c, qhi[st], qlo[st]);
        }
    }
    floatx4 zero4 = {0.f, 0.f, 0.f, 0.f};
    floatx4 Oacc[4];
#pragma unroll
    for (int t = 0; t < 4; ++t) Oacc[t] = zero4;
    float mrow[4], lrow[4];
#pragma unroll
    for (int r = 0; r < 4; ++r) { mrow[r] = -3.0e38f; lrow[r] = 0.f; }

    int nch = nkeys >> 5;
    for (int ch = 0; ch < nch; ++ch) {
        __syncthreads();
        { // stage 32 K rows + 32 V rows (transposed), split to bf16 hi/lo
            int key = tid >> 3, part = tid & 7;
            const float *kr, *vr;
            if (!gatherMode) {
                int row = b * NSEQ + ch * 32 + key;
                kr = knew + (size_t)row * DIN + h * HD;
                vr = vnew + (size_t)row * DIN + h * HD;
            } else {
                int J = ch * 32 + key;
                int mi = idxb[((size_t)h * BN + b * NSEQ + (J >> 3)) * IPQ + (J & 7)];
                if (mi < OLDN) {
                    kr = kmem0 + ((size_t)h * MEMN + BN + mi) * HD;
                    vr = vmem0 + ((size_t)h * MEMN + BN + mi) * HD;
                } else {
                    kr = knew + (size_t)(mi - OLDN) * DIN + h * HD;
                    vr = vnew + (size_t)(mi - OLDN) * DIN + h * HD;
                }
            }
            float4 ka = *(const float4*)(kr + part * 8);
            float4 kb = *(const float4*)(kr + part * 8 + 4);
            short8 kh8, kl8;
            split_pack(ka, kb, kh8, kl8);
            *(short8*)&Khi[key * 72 + part * 8] = kh8;
            *(short8*)&Klo[key * 72 + part * 8] = kl8;
            float4 va = *(const float4*)(vr + part * 8);
            float4 vb = *(const float4*)(vr + part * 8 + 4);
            float vals[8] = {va.x, va.y, va.z, va.w, vb.x, vb.y, vb.z, vb.w};
#pragma unroll
            for (int u = 0; u < 8; ++u) {
                int d = part * 8 + u;
                unsigned short hh = f2bf(vals[u]);
                Vthi[d * 40 + key] = (short)hh;
                Vtlo[d * 40 + key] = (short)f2bf(vals[u] - bf2f(hh));
            }
        }
        __syncthreads();

        // S = Q K^T (two 16-key col tiles), split-bf16 3-product
        short8 kh00 = *(const short8*)&Khi[(l16) * 72 + 0 * 32 + quad * 8];
        short8 kh01 = *(const short8*)&Khi[(l16) * 72 + 1 * 32 + quad * 8];
        short8 kl00 = *(const short8*)&Klo[(l16) * 72 + 0 * 32 + quad * 8];
        short8 kl01 = *(const short8*)&Klo[(l16) * 72 + 1 * 32 + quad * 8];
        short8 kh10 = *(const short8*)&Khi[(16 + l16) * 72 + 0 * 32 + quad * 8];
        short8 kh11 = *(const short8*)&Khi[(16 + l16) * 72 + 1 * 32 + quad * 8];
        short8 kl10 = *(const short8*)&Klo[(16 + l16) * 72 + 0 * 32 + quad * 8];
        short8 kl11 = *(const short8*)&Klo[(16 + l16) * 72 + 1 * 32 + quad * 8];
        floatx4 s0 = zero4, s1 = zero4;
        s0 = mfma16(qhi[0], kh00, s0); s0 = mfma16(qhi[1], kh01, s0);
        s0 = mfma16(qlo[0], kh00, s0); s0 = mfma16(qlo[1], kh01, s0);
        s0 = mfma16(qhi[0], kl00, s0); s0 = mfma16(qhi[1], kl01, s0);
        s1 = mfma16(qhi[0], kh10, s1); s1 = mfma16(qhi[1], kh11, s1);
        s1 = mfma16(qlo[0], kh10, s1); s1 = mfma16(qlo[1], kh11, s1);
        s1 = mfma16(qhi[0], kl10, s1); s1 = mfma16(qhi[1], kl11, s1);

        // online softmax (rows = quad*4+r, cols spread over 16 lanes)
        float cm[4], alpha[4], p0[4], p1[4], rs[4];
#pragma unroll
        for (int r = 0; r < 4; ++r) cm[r] = fmaxf(s0[r], s1[r]) * ATT_SCALE;
#pragma unroll
        for (int o = 1; o < 16; o <<= 1) {
#pragma unroll
            for (int r = 0; r < 4; ++r) cm[r] = fmaxf(cm[r], __shfl_xor(cm[r], o, 16));
        }
#pragma unroll
        for (int r = 0; r < 4; ++r) {
            float mn = fmaxf(mrow[r], cm[r]);
            alpha[r] = __expf(mrow[r] - mn);
            p0[r] = __expf(s0[r] * ATT_SCALE - mn);
            p1[r] = __expf(s1[r] * ATT_SCALE - mn);
            mrow[r] = mn;
            rs[r] = p0[r] + p1[r];
        }
#pragma unroll
        for (int o = 1; o < 16; o <<= 1) {
#pragma unroll
            for (int r = 0; r < 4; ++r) rs[r] += __shfl_xor(rs[r], o, 16);
        }
#pragma unroll
        for (int r = 0; r < 4; ++r) {
            lrow[r] = lrow[r] * alpha[r] + rs[r];
            Pbuf[(wv * 16 + quad * 4 + r) * 40 + l16] = (short)f2bf(p0[r]);
            Pbuf[(wv * 16 + quad * 4 + r) * 40 + 16 + l16] = (short)f2bf(p1[r]);
        }
#pragma unroll
        for (int t = 0; t < 4; ++t)
#pragma unroll
            for (int r = 0; r < 4; ++r) Oacc[t][r] *= alpha[r];
        __syncthreads();   // P (and Vt) visible to frag reads

        short8 pf = *(const short8*)&Pbuf[(wv * 16 + l16) * 40 + quad * 8];
#pragma unroll
        for (int t = 0; t < 4; ++t) {
            short8 vh = *(const short8*)&Vthi[(t * 16 + l16) * 40 + quad * 8];
            short8 vl = *(const short8*)&Vtlo[(t * 16 + l16) * 40 + quad * 8];
            floatx4 o = Oacc[t];
            o = mfma16(pf, vh, o);
            o = mfma16(pf, vl, o);
            Oacc[t] = o;
        }
    }
    // epilogue: divide by l, write (D rows = quad*4+r, cols = t*16+l16)
#pragma unroll
    for (int t = 0; t < 4; ++t)
#pragma unroll
        for (int r = 0; r < 4; ++r) {
            int qrow = b * NSEQ + qt * 64 + wv * 16 + quad * 4 + r;
            outp[(size_t)qrow * DIN + h * HD + t * 16 + l16] = Oacc[t][r] / lrow[r];
        }
}

// ---------------------------------------------------------------------------
// out = w*G1 + (1-w)*G2 + bo   (bias factors out of the gate)
// ---------------------------------------------------------------------------
__global__ __launch_bounds__(256) void combine_kernel(
    const float* __restrict__ G, const float* __restrict__ wg,
    const float* __restrict__ bo, float* __restrict__ out)
{
    int gid = blockIdx.x * 256 + threadIdx.x;     // f4 index, 524288 total
    float4 g1 = ((const float4*)G)[gid];
    float4 g2 = ((const float4*)G)[gid + (SZ / 4)];
    float4 w4 = ((const float4*)wg)[gid];
    float4 b4 = ((const float4*)bo)[gid & (DIN / 4 - 1)];
    float4 o;
    o.x = w4.x * g1.x + (1.f - w4.x) * g2.x + b4.x;
    o.y = w4.y * g1.y + (1.f - w4.y) * g2.y + b4.y;
    o.z = w4.z * g1.z + (1.f - w4.z) * g2.z + b4.z;
    o.w = w4.w * g1.w + (1.f - w4.w) * g2.w + b4.w;
    ((float4*)out)[gid] = o;
}

// ---------------------------------------------------------------------------
extern "C" void kernel_launch(void* const* d_in, const int* in_sizes, int n_in,
                              void* d_out, int out_size, void* d_ws, size_t ws_size,
                              hipStream_t stream)
{
    (void)in_sizes; (void)n_in; (void)out_size; (void)ws_size;
    const float* x     = (const float*)d_in[0];
    const float* Wq    = (const float*)d_in[1];
    const float* Wk    = (const float*)d_in[2];
    const float* Wv    = (const float*)d_in[3];
    const float* Ww    = (const float*)d_in[4];
    const float* Wo    = (const float*)d_in[5];
    const float* bo    = (const float*)d_in[6];
    const float* kmem0 = (const float*)d_in[7];
    const float* vmem0 = (const float*)d_in[8];

    float* ws = (float*)d_ws;
    float* q  = ws;
    float* k  = ws + (size_t)SZ;
    float* v  = ws + (size_t)2 * SZ;
    float* wg = ws + (size_t)3 * SZ;
    float* AO = ws + (size_t)4 * SZ;          // 2*SZ (rows 0..2047 = a, 2048.. = a_m)
    float* G  = ws + (size_t)6 * SZ;          // 2*SZ
    int* idxb = (int*)(ws + (size_t)8 * SZ);  // 16*2048*8
    unsigned int* nrm = (unsigned int*)(ws + (size_t)8 * SZ + NHEADS * BN * IPQ);

    init_kernel<<<1, 64, 0, stream>>>(nrm);
    gemm128<<<dim3(8, 16, 4), 256, 0, stream>>>(x, Wq, Wk, Wv, Ww, q, k, v, wg, 3);
    oldnorm_kernel<<<dim3(30, 16), 256, 0, stream>>>(kmem0, nrm);
    search_kernel<<<dim3(64, 16), 256, 0, stream>>>(q, k, kmem0, nrm, idxb);
    attn_kernel<<<dim3(8, 16, 4), 256, 0, stream>>>(q, k, v, kmem0, vmem0, idxb, AO, 0, 512);
    attn_kernel<<<dim3(8, 16, 4), 256, 0, stream>>>(q, k, v, kmem0, vmem0, idxb,
                                                    AO + (size_t)SZ, 1, 4096);
    gemm128<<<dim3(8, 32, 1), 256, 0, stream>>>(AO, Wo, Wo, Wo, Wo, G, G, G, G, -1);
    combine_kernel<<<2048, 256, 0, stream>>>(G, wg, bo, (float*)d_out);
}

// Round 2
// 1221.292 us; speedup vs baseline: 7.7026x; 7.7026x over previous
//
#include <hip/hip_runtime.h>
#include <float.h>
#include <math.h>

// ---------------------------------------------------------------------------
// MABlock: q/k/v/w projections -> attn over batch keys -> FAISS-style exact
// top-8 retrieval from FIFO memory -> attn over retrieved keys -> Wo + gate.
//
// Round 2: replace spilled fp32 VALU GEMM (16.4 GB scratch traffic, 5.5 ms)
// with MFMA split-bf16 GEMM (4-product: Ah*Bh+Ah*Bl+Al*Bh+Al*Bl, error
// ~2^-18 rel — keeps q/k at fp32-grade accuracy so the exact top-8 is safe).
// fp32 -> (hi,lo) bf16 conversion happens during LDS staging; no extra ws.
// ---------------------------------------------------------------------------

#define DIN   1024
#define NHEADS 16
#define HD    64
#define NB    4
#define NSEQ  512
#define BN    2048          // NB*NSEQ
#define MEMN  32768
#define OLDN  30720         // MEMN - BN
#define IPQ   8
#define ATT_SCALE 0.125f
#define SZ    (BN * DIN)    // 2097152 floats

typedef __attribute__((ext_vector_type(4))) float floatx4;
typedef __attribute__((ext_vector_type(8))) short short8;

__device__ __forceinline__ unsigned short f2bf(float f) {
    unsigned int u = __float_as_uint(f);
    return (unsigned short)((u + 0x7FFFu + ((u >> 16) & 1u)) >> 16);
}
__device__ __forceinline__ float bf2f(unsigned short s) {
    return __uint_as_float(((unsigned int)s) << 16);
}
__device__ __forceinline__ void split_pack(float4 a, float4 b, short8 &hi, short8 &lo) {
    float vals[8] = {a.x, a.y, a.z, a.w, b.x, b.y, b.z, b.w};
#pragma unroll
    for (int j = 0; j < 8; ++j) {
        unsigned short h = f2bf(vals[j]);
        hi[j] = (short)h;
        lo[j] = (short)f2bf(vals[j] - bf2f(h));
    }
}
__device__ __forceinline__ floatx4 mfma16(short8 a, short8 b, floatx4 c) {
    return __builtin_amdgcn_mfma_f32_16x16x32_bf16(a, b, c, 0, 0, 0);
}

// ---------------------------------------------------------------------------
// init: zero the 16 per-head max-old-norm slots (ws is poisoned 0xAA)
// ---------------------------------------------------------------------------
__global__ void init_kernel(unsigned int* nrm) {
    if (threadIdx.x < NHEADS) nrm[threadIdx.x] = 0u;
}

// ---------------------------------------------------------------------------
// MFMA GEMM: C[z][M][1024] = A[M][1024] @ W[z][1024][1024]^T (NT, k-major).
// 128x128 block tile, 4 waves in 2x2 of 64x64 wave tiles, K-step 32.
// Staging converts fp32 -> split bf16 (hi,lo) into LDS; 4-product mfma.
// C/D layout per 16x16 subtile: row = quad*4+reg, col = l16.
// sigmoidZ: z index that gets a sigmoid epilogue (-1 = none).
// ---------------------------------------------------------------------------
__global__ __launch_bounds__(256) void gemm_mfma(
    const float* __restrict__ A,
    const float* __restrict__ W0, const float* __restrict__ W1,
    const float* __restrict__ W2, const float* __restrict__ W3,
    float* __restrict__ C0, float* __restrict__ C1,
    float* __restrict__ C2, float* __restrict__ C3,
    int sigmoidZ)
{
    __shared__ short Ahi_s[128 * 32];
    __shared__ short Alo_s[128 * 32];
    __shared__ short Bhi_s[128 * 32];
    __shared__ short Blo_s[128 * 32];

    int z = blockIdx.z;
    const float* W = (z == 0) ? W0 : (z == 1) ? W1 : (z == 2) ? W2 : W3;
    float* C = (z == 0) ? C0 : (z == 1) ? C1 : (z == 2) ? C2 : C3;

    int tid = threadIdx.x;
    int wv = tid >> 6, lane = tid & 63, quad = lane >> 4, l16 = lane & 15;
    int row0 = blockIdx.y * 128, col0 = blockIdx.x * 128;
    int wm = (wv >> 1) * 64, wn = (wv & 1) * 64;

    floatx4 zero4 = {0.f, 0.f, 0.f, 0.f};
    floatx4 acc[4][4];
#pragma unroll
    for (int i = 0; i < 4; ++i)
#pragma unroll
        for (int j = 0; j < 4; ++j) acc[i][j] = zero4;

    for (int kk = 0; kk < DIN; kk += 32) {
        __syncthreads();
        // stage 128x32 of A and W, split fp32 -> bf16 hi/lo
#pragma unroll
        for (int p = 0; p < 2; ++p) {
            int g = tid * 2 + p;              // 8-float group, 0..511
            int row = g >> 2, cc = (g & 3) * 8;
            const float* ap = A + (size_t)(row0 + row) * DIN + kk + cc;
            float4 a0 = *(const float4*)ap;
            float4 a1 = *(const float4*)(ap + 4);
            short8 h8, l8;
            split_pack(a0, a1, h8, l8);
            *(short8*)&Ahi_s[g * 8] = h8;
            *(short8*)&Alo_s[g * 8] = l8;
            const float* bp = W + (size_t)(col0 + row) * DIN + kk + cc;
            float4 b0 = *(const float4*)bp;
            float4 b1 = *(const float4*)(bp + 4);
            split_pack(b0, b1, h8, l8);
            *(short8*)&Bhi_s[g * 8] = h8;
            *(short8*)&Blo_s[g * 8] = l8;
        }
        __syncthreads();

        short8 ah[4], al[4], bh[4], bl[4];
#pragma unroll
        for (int t = 0; t < 4; ++t) {
            int ar = (wm + t * 16 + l16) * 32 + quad * 8;
            int br = (wn + t * 16 + l16) * 32 + quad * 8;
            ah[t] = *(const short8*)&Ahi_s[ar];
            al[t] = *(const short8*)&Alo_s[ar];
            bh[t] = *(const short8*)&Bhi_s[br];
            bl[t] = *(const short8*)&Blo_s[br];
        }
#pragma unroll
        for (int tm = 0; tm < 4; ++tm)
#pragma unroll
            for (int tn = 0; tn < 4; ++tn) {
                floatx4 c = acc[tm][tn];
                c = mfma16(al[tm], bl[tn], c);
                c = mfma16(al[tm], bh[tn], c);
                c = mfma16(ah[tm], bl[tn], c);
                c = mfma16(ah[tm], bh[tn], c);
                acc[tm][tn] = c;
            }
    }

    bool sig = (sigmoidZ == z);
#pragma unroll
    for (int tm = 0; tm < 4; ++tm)
#pragma unroll
        for (int tn = 0; tn < 4; ++tn)
#pragma unroll
            for (int r = 0; r < 4; ++r) {
                int row = row0 + wm + tm * 16 + quad * 4 + r;
                int col = col0 + wn + tn * 16 + l16;
                float vv = acc[tm][tn][r];
                if (sig) vv = 1.f / (1.f + __expf(-vv));
                C[(size_t)row * DIN + col] = vv;
            }
}

// ---------------------------------------------------------------------------
// per-head max L2 norm over the 30720 surviving old memory keys
// grid (30, 16), 256 threads; 16 lanes per row.
// ---------------------------------------------------------------------------
__global__ __launch_bounds__(256) void oldnorm_kernel(
    const float* __restrict__ kmem0, unsigned int* __restrict__ nrm)
{
    int h = blockIdx.y;
    int c0 = blockIdx.x * 1024;
    int part = threadIdx.x & 15, rg = threadIdx.x >> 4;
    const float* base = kmem0 + ((size_t)h * MEMN + BN) * HD;
    float mx = 0.f;
    for (int it = 0; it < 64; ++it) {
        int row = c0 + it * 16 + rg;
        float4 vv = *(const float4*)(base + (size_t)row * HD + part * 4);
        float s = vv.x * vv.x + vv.y * vv.y + vv.z * vv.z + vv.w * vv.w;
#pragma unroll
        for (int o = 1; o < 16; o <<= 1) s += __shfl_xor(s, o, 16);
        mx = fmaxf(mx, s);
    }
    __shared__ float red[256];
    red[threadIdx.x] = mx;
    __syncthreads();
    for (int st = 128; st > 0; st >>= 1) {
        if (threadIdx.x < st) red[threadIdx.x] = fmaxf(red[threadIdx.x], red[threadIdx.x + st]);
        __syncthreads();
    }
    if (threadIdx.x == 0) atomicMax(nrm + h, __float_as_uint(sqrtf(red[0])));
}

// ---------------------------------------------------------------------------
// search: per (h, 32-query block) exact top-8.
// Phase A: scan the 2048 new keys (chunks of 128 staged in LDS).
// Merge per query over its 32-lane group (val desc, idx asc — matches top_k).
// Bound check |q|*maxOldNorm >= val8 -> exact old-memory scan (fallback).
// ---------------------------------------------------------------------------
__device__ __forceinline__ void insert_top8(float (&tv)[8], int (&ti)[8], float v, int id) {
    if (v < tv[7] || (v == tv[7] && id > ti[7])) return;
    tv[7] = v; ti[7] = id;
#pragma unroll
    for (int s = 7; s > 0; --s) {
        bool sw = (tv[s] > tv[s - 1]) || (tv[s] == tv[s - 1] && ti[s] < ti[s - 1]);
        if (sw) {
            float fv = tv[s]; tv[s] = tv[s - 1]; tv[s - 1] = fv;
            int iv = ti[s]; ti[s] = ti[s - 1]; ti[s - 1] = iv;
        }
    }
}

__global__ __launch_bounds__(256, 2) void search_kernel(
    const float* __restrict__ q, const float* __restrict__ knew,
    const float* __restrict__ kmem0, const unsigned int* __restrict__ nrm,
    int* __restrict__ idxOut)
{
    __shared__ float qT[32 * 68];
    __shared__ float Kc[128 * 68];
    __shared__ float qn2s[32];
    __shared__ int sflag;
    int h = blockIdx.y;
    int t0 = blockIdx.x * 32;
    int tid = threadIdx.x;
    int qg = tid >> 5;   // 0..7, queries qg*4..+4
    int kt = tid & 31;   // key thread 0..31, keys kt+32u
    if (tid == 0) sflag = 0;

    { // stage 32 query rows
        int c4 = tid & 15, r = tid >> 4;
#pragma unroll
        for (int p = 0; p < 2; ++p) {
            int row = p * 16 + r;
            float4 vv = *(const float4*)(q + (size_t)(t0 + row) * DIN + h * HD + c4 * 4);
            int sw = (row + (row >> 3)) & 7;
            *(float4*)&qT[row * 68 + ((c4 ^ sw) << 2)] = vv;
        }
    }
    __syncthreads();
    if (tid < 32) { // |q|^2 (order-independent: sum all physical slots)
        float s = 0.f;
#pragma unroll
        for (int c4 = 0; c4 < 16; ++c4) {
            float4 vv = *(const float4*)&qT[tid * 68 + c4 * 4];
            s += vv.x * vv.x + vv.y * vv.y + vv.z * vv.z + vv.w * vv.w;
        }
        qn2s[tid] = s;
    }

    float tv[4][8]; int ti[4][8];
#pragma unroll
    for (int qi = 0; qi < 4; ++qi)
#pragma unroll
        for (int s = 0; s < 8; ++s) { tv[qi][s] = -FLT_MAX; ti[qi][s] = 0x7FFFFFFF; }

    // ---- phase A: new keys ----
    for (int ch = 0; ch < 16; ++ch) {
        __syncthreads();
        {
            int c4 = tid & 15, r = tid >> 4;
#pragma unroll
            for (int p = 0; p < 8; ++p) {
                int row = p * 16 + r;
                float4 vv = *(const float4*)(knew + (size_t)(ch * 128 + row) * DIN + h * HD + c4 * 4);
                int sw = (row + (row >> 3)) & 7;
                *(float4*)&Kc[row * 68 + ((c4 ^ sw) << 2)] = vv;
            }
        }
        __syncthreads();
        float ps[4][4];
#pragma unroll
        for (int a = 0; a < 4; ++a)
#pragma unroll
            for (int b = 0; b < 4; ++b) ps[a][b] = 0.f;
        for (int c4 = 0; c4 < 16; ++c4) {
            float4 qf[4], kf[4];
#pragma unroll
            for (int qi = 0; qi < 4; ++qi) {
                int tq = qg * 4 + qi;
                qf[qi] = *(const float4*)&qT[tq * 68 + ((c4 ^ ((tq + (tq >> 3)) & 7)) << 2)];
            }
#pragma unroll
            for (int u = 0; u < 4; ++u) {
                int kr = kt + 32 * u;
                kf[u] = *(const float4*)&Kc[kr * 68 + ((c4 ^ ((kr + (kr >> 3)) & 7)) << 2)];
            }
#pragma unroll
            for (int qi = 0; qi < 4; ++qi)
#pragma unroll
                for (int u = 0; u < 4; ++u)
                    ps[qi][u] += qf[qi].x * kf[u].x + qf[qi].y * kf[u].y
                               + qf[qi].z * kf[u].z + qf[qi].w * kf[u].w;
        }
#pragma unroll
        for (int qi = 0; qi < 4; ++qi)
#pragma unroll
            for (int u = 0; u < 4; ++u)
                insert_top8(tv[qi], ti[qi], ps[qi][u], OLDN + ch * 128 + kt + 32 * u);
    }

    // ---- merge #1 (consumes lists; captures winners for possible rebuild) ----
    float val8[4], keepv[4];
    int keepi[4];
#pragma unroll
    for (int qi = 0; qi < 4; ++qi) { keepv[qi] = -FLT_MAX; keepi[qi] = 0x7FFFFFFF; val8[qi] = -FLT_MAX; }
#pragma unroll
    for (int qi = 0; qi < 4; ++qi) {
#pragma unroll
        for (int r = 0; r < 8; ++r) {
            float cv = tv[qi][0]; int ci = ti[qi][0];
#pragma unroll
            for (int o = 1; o < 32; o <<= 1) {
                float ov = __shfl_xor(cv, o, 32);
                int oi = __shfl_xor(ci, o, 32);
                if (ov > cv || (ov == cv && oi < ci)) { cv = ov; ci = oi; }
            }
            if (tv[qi][0] == cv && ti[qi][0] == ci) {
#pragma unroll
                for (int s = 0; s < 7; ++s) { tv[qi][s] = tv[qi][s + 1]; ti[qi][s] = ti[qi][s + 1]; }
                tv[qi][7] = -FLT_MAX; ti[qi][7] = 0x7FFFFFFF;
            }
            if (kt == r) { keepv[qi] = cv; keepi[qi] = ci; }
            if (kt == 0) idxOut[((size_t)h * BN + t0 + qg * 4 + qi) * IPQ + r] = ci;
            val8[qi] = cv;
        }
    }

    // ---- bound check: can any old key enter the top-8? ----
    float oldMax = __uint_as_float(nrm[h]);
    bool need = false;
#pragma unroll
    for (int qi = 0; qi < 4; ++qi) {
        float bnd = sqrtf(qn2s[qg * 4 + qi]) * oldMax * 1.0001f + 1e-5f;
        if (bnd >= val8[qi]) need = true;
    }
    if (need) sflag = 1;
    __syncthreads();

    if (sflag) {
        // rebuild per-lane lists: lane r<8 holds winner r, rest empty
#pragma unroll
        for (int qi = 0; qi < 4; ++qi) {
            tv[qi][0] = (kt < 8) ? keepv[qi] : -FLT_MAX;
            ti[qi][0] = (kt < 8) ? keepi[qi] : 0x7FFFFFFF;
#pragma unroll
            for (int s = 1; s < 8; ++s) { tv[qi][s] = -FLT_MAX; ti[qi][s] = 0x7FFFFFFF; }
        }
        for (int ch = 0; ch < 240; ++ch) {
            __syncthreads();
            {
                int c4 = tid & 15, r = tid >> 4;
#pragma unroll
                for (int p = 0; p < 8; ++p) {
                    int row = p * 16 + r;
                    float4 vv = *(const float4*)(kmem0 + ((size_t)h * MEMN + BN + ch * 128 + row) * HD + c4 * 4);
                    int sw = (row + (row >> 3)) & 7;
                    *(float4*)&Kc[row * 68 + ((c4 ^ sw) << 2)] = vv;
                }
            }
            __syncthreads();
            float ps[4][4];
#pragma unroll
            for (int a = 0; a < 4; ++a)
#pragma unroll
                for (int b = 0; b < 4; ++b) ps[a][b] = 0.f;
            for (int c4 = 0; c4 < 16; ++c4) {
                float4 qf[4], kf[4];
#pragma unroll
                for (int qi = 0; qi < 4; ++qi) {
                    int tq = qg * 4 + qi;
                    qf[qi] = *(const float4*)&qT[tq * 68 + ((c4 ^ ((tq + (tq >> 3)) & 7)) << 2)];
                }
#pragma unroll
                for (int u = 0; u < 4; ++u) {
                    int kr = kt + 32 * u;
                    kf[u] = *(const float4*)&Kc[kr * 68 + ((c4 ^ ((kr + (kr >> 3)) & 7)) << 2)];
                }
#pragma unroll
                for (int qi = 0; qi < 4; ++qi)
#pragma unroll
                    for (int u = 0; u < 4; ++u)
                        ps[qi][u] += qf[qi].x * kf[u].x + qf[qi].y * kf[u].y
                                   + qf[qi].z * kf[u].z + qf[qi].w * kf[u].w;
            }
#pragma unroll
            for (int qi = 0; qi < 4; ++qi)
#pragma unroll
                for (int u = 0; u < 4; ++u)
                    insert_top8(tv[qi], ti[qi], ps[qi][u], ch * 128 + kt + 32 * u);
        }
        // merge #2 (final)
#pragma unroll
        for (int qi = 0; qi < 4; ++qi) {
#pragma unroll
            for (int r = 0; r < 8; ++r) {
                float cv = tv[qi][0]; int ci = ti[qi][0];
#pragma unroll
                for (int o = 1; o < 32; o <<= 1) {
                    float ov = __shfl_xor(cv, o, 32);
                    int oi = __shfl_xor(ci, o, 32);
                    if (ov > cv || (ov == cv && oi < ci)) { cv = ov; ci = oi; }
                }
                if (tv[qi][0] == cv && ti[qi][0] == ci) {
#pragma unroll
                    for (int s = 0; s < 7; ++s) { tv[qi][s] = tv[qi][s + 1]; ti[qi][s] = ti[qi][s + 1]; }
                    tv[qi][7] = -FLT_MAX; ti[qi][7] = 0x7FFFFFFF;
                }
                if (kt == 0) idxOut[((size_t)h * BN + t0 + qg * 4 + qi) * IPQ + r] = ci;
            }
        }
    }
}

// ---------------------------------------------------------------------------
// MFMA flash attention. Block = 4 waves x 16 queries = 64 queries per (b,h).
// Per 32-key chunk: stage K (hi/lo bf16, row-major) and V^T (hi/lo, dim-major)
// in LDS; S = QK^T via 3-product split-bf16 mfma; online softmax per wave
// (quad-row layout, width-16 shuffles); P round-trips LDS to A-frag layout;
// O += P*Vhi + P*Vlo.  gatherMode=1 resolves rows through idx (memory attn).
// ---------------------------------------------------------------------------
__global__ __launch_bounds__(256, 2) void attn_kernel(
    const float* __restrict__ q, const float* __restrict__ knew,
    const float* __restrict__ vnew, const float* __restrict__ kmem0,
    const float* __restrict__ vmem0, const int* __restrict__ idxb,
    float* __restrict__ outp, int gatherMode, int nkeys)
{
    __shared__ short Khi[32 * 72];
    __shared__ short Klo[32 * 72];
    __shared__ short Vthi[64 * 40];
    __shared__ short Vtlo[64 * 40];
    __shared__ short Pbuf[4 * 16 * 40];
    int tid = threadIdx.x;
    int qt = blockIdx.x, h = blockIdx.y, b = blockIdx.z;
    int wv = tid >> 6, lane = tid & 63, quad = lane >> 4, l16 = lane & 15;

    // persistent Q fragments (A-operand layout: row=l16, k=quad*8+j, step*32)
    short8 qhi[2], qlo[2];
    {
        int qrow = b * NSEQ + qt * 64 + wv * 16 + l16;
        const float* qp = q + (size_t)qrow * DIN + h * HD;
#pragma unroll
        for (int st = 0; st < 2; ++st) {
            float4 a = *(const float4*)(qp + st * 32 + quad * 8);
            float4 c = *(const float4*)(qp + st * 32 + quad * 8 + 4);
            split_pack(a, c, qhi[st], qlo[st]);
        }
    }
    floatx4 zero4 = {0.f, 0.f, 0.f, 0.f};
    floatx4 Oacc[4];
#pragma unroll
    for (int t = 0; t < 4; ++t) Oacc[t] = zero4;
    float mrow[4], lrow[4];
#pragma unroll
    for (int r = 0; r < 4; ++r) { mrow[r] = -3.0e38f; lrow[r] = 0.f; }

    int nch = nkeys >> 5;
    for (int ch = 0; ch < nch; ++ch) {
        __syncthreads();
        { // stage 32 K rows + 32 V rows (transposed), split to bf16 hi/lo
            int key = tid >> 3, part = tid & 7;
            const float *kr, *vr;
            if (!gatherMode) {
                int row = b * NSEQ + ch * 32 + key;
                kr = knew + (size_t)row * DIN + h * HD;
                vr = vnew + (size_t)row * DIN + h * HD;
            } else {
                int J = ch * 32 + key;
                int mi = idxb[((size_t)h * BN + b * NSEQ + (J >> 3)) * IPQ + (J & 7)];
                if (mi < OLDN) {
                    kr = kmem0 + ((size_t)h * MEMN + BN + mi) * HD;
                    vr = vmem0 + ((size_t)h * MEMN + BN + mi) * HD;
                } else {
                    kr = knew + (size_t)(mi - OLDN) * DIN + h * HD;
                    vr = vnew + (size_t)(mi - OLDN) * DIN + h * HD;
                }
            }
            float4 ka = *(const float4*)(kr + part * 8);
            float4 kb = *(const float4*)(kr + part * 8 + 4);
            short8 kh8, kl8;
            split_pack(ka, kb, kh8, kl8);
            *(short8*)&Khi[key * 72 + part * 8] = kh8;
            *(short8*)&Klo[key * 72 + part * 8] = kl8;
            float4 va = *(const float4*)(vr + part * 8);
            float4 vb = *(const float4*)(vr + part * 8 + 4);
            float vals[8] = {va.x, va.y, va.z, va.w, vb.x, vb.y, vb.z, vb.w};
#pragma unroll
            for (int u = 0; u < 8; ++u) {
                int d = part * 8 + u;
                unsigned short hh = f2bf(vals[u]);
                Vthi[d * 40 + key] = (short)hh;
                Vtlo[d * 40 + key] = (short)f2bf(vals[u] - bf2f(hh));
            }
        }
        __syncthreads();

        // S = Q K^T (two 16-key col tiles), split-bf16 3-product
        short8 kh00 = *(const short8*)&Khi[(l16) * 72 + 0 * 32 + quad * 8];
        short8 kh01 = *(const short8*)&Khi[(l16) * 72 + 1 * 32 + quad * 8];
        short8 kl00 = *(const short8*)&Klo[(l16) * 72 + 0 * 32 + quad * 8];
        short8 kl01 = *(const short8*)&Klo[(l16) * 72 + 1 * 32 + quad * 8];
        short8 kh10 = *(const short8*)&Khi[(16 + l16) * 72 + 0 * 32 + quad * 8];
        short8 kh11 = *(const short8*)&Khi[(16 + l16) * 72 + 1 * 32 + quad * 8];
        short8 kl10 = *(const short8*)&Klo[(16 + l16) * 72 + 0 * 32 + quad * 8];
        short8 kl11 = *(const short8*)&Klo[(16 + l16) * 72 + 1 * 32 + quad * 8];
        floatx4 s0 = zero4, s1 = zero4;
        s0 = mfma16(qhi[0], kh00, s0); s0 = mfma16(qhi[1], kh01, s0);
        s0 = mfma16(qlo[0], kh00, s0); s0 = mfma16(qlo[1], kh01, s0);
        s0 = mfma16(qhi[0], kl00, s0); s0 = mfma16(qhi[1], kl01, s0);
        s1 = mfma16(qhi[0], kh10, s1); s1 = mfma16(qhi[1], kh11, s1);
        s1 = mfma16(qlo[0], kh10, s1); s1 = mfma16(qlo[1], kh11, s1);
        s1 = mfma16(qhi[0], kl10, s1); s1 = mfma16(qhi[1], kl11, s1);

        // online softmax (rows = quad*4+r, cols spread over 16 lanes)
        float cm[4], alpha[4], p0[4], p1[4], rs[4];
#pragma unroll
        for (int r = 0; r < 4; ++r) cm[r] = fmaxf(s0[r], s1[r]) * ATT_SCALE;
#pragma unroll
        for (int o = 1; o < 16; o <<= 1) {
#pragma unroll
            for (int r = 0; r < 4; ++r) cm[r] = fmaxf(cm[r], __shfl_xor(cm[r], o, 16));
        }
#pragma unroll
        for (int r = 0; r < 4; ++r) {
            float mn = fmaxf(mrow[r], cm[r]);
            alpha[r] = __expf(mrow[r] - mn);
            p0[r] = __expf(s0[r] * ATT_SCALE - mn);
            p1[r] = __expf(s1[r] * ATT_SCALE - mn);
            mrow[r] = mn;
            rs[r] = p0[r] + p1[r];
        }
#pragma unroll
        for (int o = 1; o < 16; o <<= 1) {
#pragma unroll
            for (int r = 0; r < 4; ++r) rs[r] += __shfl_xor(rs[r], o, 16);
        }
#pragma unroll
        for (int r = 0; r < 4; ++r) {
            lrow[r] = lrow[r] * alpha[r] + rs[r];
            Pbuf[(wv * 16 + quad * 4 + r) * 40 + l16] = (short)f2bf(p0[r]);
            Pbuf[(wv * 16 + quad * 4 + r) * 40 + 16 + l16] = (short)f2bf(p1[r]);
        }
#pragma unroll
        for (int t = 0; t < 4; ++t)
#pragma unroll
            for (int r = 0; r < 4; ++r) Oacc[t][r] *= alpha[r];
        __syncthreads();   // P (and Vt) visible to frag reads

        short8 pf = *(const short8*)&Pbuf[(wv * 16 + l16) * 40 + quad * 8];
#pragma unroll
        for (int t = 0; t < 4; ++t) {
            short8 vh = *(const short8*)&Vthi[(t * 16 + l16) * 40 + quad * 8];
            short8 vl = *(const short8*)&Vtlo[(t * 16 + l16) * 40 + quad * 8];
            floatx4 o = Oacc[t];
            o = mfma16(pf, vh, o);
            o = mfma16(pf, vl, o);
            Oacc[t] = o;
        }
    }
    // epilogue: divide by l, write (D rows = quad*4+r, cols = t*16+l16)
#pragma unroll
    for (int t = 0; t < 4; ++t)
#pragma unroll
        for (int r = 0; r < 4; ++r) {
            int qrow = b * NSEQ + qt * 64 + wv * 16 + quad * 4 + r;
            outp[(size_t)qrow * DIN + h * HD + t * 16 + l16] = Oacc[t][r] / lrow[r];
        }
}

// ---------------------------------------------------------------------------
// out = w*G1 + (1-w)*G2 + bo   (bias factors out of the gate)
// ---------------------------------------------------------------------------
__global__ __launch_bounds__(256) void combine_kernel(
    const float* __restrict__ G, const float* __restrict__ wg,
    const float* __restrict__ bo, float* __restrict__ out)
{
    int gid = blockIdx.x * 256 + threadIdx.x;     // f4 index, 524288 total
    float4 g1 = ((const float4*)G)[gid];
    float4 g2 = ((const float4*)G)[gid + (SZ / 4)];
    float4 w4 = ((const float4*)wg)[gid];
    float4 b4 = ((const float4*)bo)[gid & (DIN / 4 - 1)];
    float4 o;
    o.x = w4.x * g1.x + (1.f - w4.x) * g2.x + b4.x;
    o.y = w4.y * g1.y + (1.f - w4.y) * g2.y + b4.y;
    o.z = w4.z * g1.z + (1.f - w4.z) * g2.z + b4.z;
    o.w = w4.w * g1.w + (1.f - w4.w) * g2.w + b4.w;
    ((float4*)out)[gid] = o;
}

// ---------------------------------------------------------------------------
extern "C" void kernel_launch(void* const* d_in, const int* in_sizes, int n_in,
                              void* d_out, int out_size, void* d_ws, size_t ws_size,
                              hipStream_t stream)
{
    (void)in_sizes; (void)n_in; (void)out_size; (void)ws_size;
    const float* x     = (const float*)d_in[0];
    const float* Wq    = (const float*)d_in[1];
    const float* Wk    = (const float*)d_in[2];
    const float* Wv    = (const float*)d_in[3];
    const float* Ww    = (const float*)d_in[4];
    const float* Wo    = (const float*)d_in[5];
    const float* bo    = (const float*)d_in[6];
    const float* kmem0 = (const float*)d_in[7];
    const float* vmem0 = (const float*)d_in[8];

    float* ws = (float*)d_ws;
    float* q  = ws;
    float* k  = ws + (size_t)SZ;
    float* v  = ws + (size_t)2 * SZ;
    float* wg = ws + (size_t)3 * SZ;
    float* AO = ws + (size_t)4 * SZ;          // 2*SZ (rows 0..2047 = a, 2048.. = a_m)
    float* G  = ws + (size_t)6 * SZ;          // 2*SZ
    int* idxb = (int*)(ws + (size_t)8 * SZ);  // 16*2048*8
    unsigned int* nrm = (unsigned int*)(ws + (size_t)8 * SZ + NHEADS * BN * IPQ);

    init_kernel<<<1, 64, 0, stream>>>(nrm);
    gemm_mfma<<<dim3(8, 16, 4), 256, 0, stream>>>(x, Wq, Wk, Wv, Ww, q, k, v, wg, 3);
    oldnorm_kernel<<<dim3(30, 16), 256, 0, stream>>>(kmem0, nrm);
    search_kernel<<<dim3(64, 16), 256, 0, stream>>>(q, k, kmem0, nrm, idxb);
    attn_kernel<<<dim3(8, 16, 4), 256, 0, stream>>>(q, k, v, kmem0, vmem0, idxb, AO, 0, 512);
    attn_kernel<<<dim3(8, 16, 4), 256, 0, stream>>>(q, k, v, kmem0, vmem0, idxb,
                                                    AO + (size_t)SZ, 1, 4096);
    gemm_mfma<<<dim3(8, 32, 1), 256, 0, stream>>>(AO, Wo, Wo, Wo, Wo, G, G, G, G, -1);
    combine_kernel<<<2048, 256, 0, stream>>>(G, wg, bo, (float*)d_out);
}